// Round 10
// baseline (262.504 us; speedup 1.0000x reference)
//
#include <hip/hip_runtime.h>
#include <cstdint>

static constexpr int C     = 5;
static constexpr int MAXP  = 10;
static constexpr int MAXV  = 160000;
static constexpr int BLK   = 256;
static constexpr int RBITS = 9;
static constexpr int RBUCK = 1 << RBITS;   // 512 buckets
static constexpr int EPT   = 8;            // elements per thread
static constexpr int ELEMS = BLK * EPT;    // 2048 elements per block

// Output layout (float32, concatenated in reference return order)
static constexpr int VOX_OFF = 0;                           // 160000*10*5
static constexpr int CO_OFF  = MAXV * MAXP * C;             // 8,000,000
static constexpr int NPV_OFF = CO_OFF + MAXV * 3;           // 8,480,000
static constexpr int VN_OFF  = NPV_OFF + MAXV;              // 8,640,000

typedef unsigned long long u64;
static constexpr u64 BYTEMUL = 0x0101010101010101ull;
static constexpr u64 FLAGP   = 1ull << 62;
static constexpr u64 FLAGX   = 2ull << 62;
static constexpr u64 M28     = (1ull << 28) - 1;

// K1: quantize -> int keys AND pass-0 block histogram (fused); zero lookback statuses.
__global__ void kv10_linhist(const float* __restrict__ pts, const float* __restrict__ vsz,
                             const float* __restrict__ crg, int* __restrict__ key0,
                             int* __restrict__ hist, int* __restrict__ ctrl,
                             u64* __restrict__ statusH, u64* __restrict__ statusW,
                             int NP, int NB, int NWB) {
    __shared__ int sh[RBUCK];
    int t = threadIdx.x, b = blockIdx.x;
    int gid = b * BLK + t;
    if (gid < NB) statusH[gid] = 0ull;
    if (gid < NWB) statusW[gid] = 0ull;
    for (int d = t; d < RBUCK; d += BLK) sh[d] = 0;
    float vx = vsz[0], vy = vsz[1], vz = vsz[2];
    float x0 = crg[0], y0 = crg[1], z0 = crg[2];
    int gx = (int)rintf((crg[3] - x0) / vx);
    int gy = (int)rintf((crg[4] - y0) / vy);
    int gz = (int)rintf((crg[5] - z0) / vz);
    int total = gx * gy * gz;
    if (b == 0 && t == 0) ctrl[2] = total;
    __syncthreads();
    int base = b * ELEMS;
    #pragma unroll
    for (int r = 0; r < EPT; r++) {
        int i = base + r * BLK + t;
        if (i < NP) {
            float px = pts[i * C], py = pts[i * C + 1], pz = pts[i * C + 2];
            int cx = (int)floorf((px - x0) / vx);
            int cy = (int)floorf((py - y0) / vy);
            int cz = (int)floorf((pz - z0) / vz);
            bool valid = (cx >= 0) & (cx < gx) & (cy >= 0) & (cy < gy) & (cz >= 0) & (cz < gz);
            int k = valid ? (cx * gy + cy) * gz + cz : total;
            key0[i] = k;
            atomicAdd(&sh[k & (RBUCK - 1)], 1);
        }
    }
    __syncthreads();
    for (int d = t; d < RBUCK; d += BLK) hist[b * RBUCK + d] = sh[d];
}

// Histogram, passes 1..2 (u64 pairs, digit from high 32 bits).
__global__ void kv10_hist_p(const u64* __restrict__ pair, int* __restrict__ hist,
                            int NP, int shift) {
    __shared__ int sh[RBUCK];
    int t = threadIdx.x, b = blockIdx.x;
    for (int d = t; d < RBUCK; d += BLK) sh[d] = 0;
    __syncthreads();
    int base = b * ELEMS;
    #pragma unroll
    for (int r = 0; r < EPT; r++) {
        int i = base + r * BLK + t;
        if (i < NP) atomicAdd(&sh[(int)((pair[i] >> (32 + shift)) & (RBUCK - 1))], 1);
    }
    __syncthreads();
    for (int d = t; d < RBUCK; d += BLK) hist[b * RBUCK + d] = sh[d];
}

// Per-digit exclusive scan across blocks (grid = RBUCK; block d owns digit d).
__global__ void kv10_scanb(int* __restrict__ hist, int* __restrict__ dtot, int NB) {
    __shared__ int s[BLK];
    __shared__ int carry;
    int d = blockIdx.x, t = threadIdx.x;
    if (t == 0) carry = 0;
    __syncthreads();
    for (int base = 0; base < NB; base += BLK) {
        int b = base + t;
        int v = (b < NB) ? hist[b * RBUCK + d] : 0;
        s[t] = v; __syncthreads();
        for (int o = 1; o < BLK; o <<= 1) {
            int x = (t >= o) ? s[t - o] : 0; __syncthreads();
            s[t] += x; __syncthreads();
        }
        int incl = s[t], c = carry;
        if (b < NB) hist[b * RBUCK + d] = c + incl - v;
        __syncthreads();
        if (t == BLK - 1) carry = c + incl;
        __syncthreads();
    }
    if (t == 0) dtot[d] = carry;
}

// Stable scatter. dbase computed in-block (wave-0 scan of dtot, 1 sync).
// Round-tagged whist (no zeroing); 2 syncs per sub-batch round.
#define SCAT10_BODY(GET_KEY, GET_IDX)                                           \
    __shared__ int cnt[RBUCK];                                                  \
    __shared__ int dbS[RBUCK];                                                  \
    __shared__ int whist[4][RBUCK];                                             \
    int t = threadIdx.x, b = blockIdx.x;                                        \
    int w = t >> 6, lane = t & 63;                                              \
    if (t < 64) {                                                               \
        int loc[8]; int run = 0;                                                \
        _Pragma("unroll")                                                       \
        for (int j = 0; j < 8; j++) { loc[j] = run; run += dtot[t * 8 + j]; }   \
        int tot = run;                                                          \
        for (int o = 1; o < 64; o <<= 1) {                                      \
            int x = __shfl_up(tot, o, 64);                                      \
            if (lane >= o) tot += x;                                            \
        }                                                                       \
        int excl = tot - run;                                                   \
        _Pragma("unroll")                                                       \
        for (int j = 0; j < 8; j++) dbS[t * 8 + j] = excl + loc[j];             \
    }                                                                           \
    for (int x = t; x < 4 * RBUCK; x += BLK) ((int*)whist)[x] = -1;             \
    __syncthreads();                                                            \
    for (int d = t; d < RBUCK; d += BLK) cnt[d] = dbS[d] + hist[b * RBUCK + d]; \
    __syncthreads();                                                            \
    int base = b * ELEMS;                                                       \
    int nc0 = 0, nc1 = 0; bool havenc = false;                                  \
    for (int r = 0; r < EPT; r++) {                                             \
        int i = base + r * BLK + t;                                             \
        bool act = i < NP;                                                      \
        int k = 0, idx = 0, d = 0;                                              \
        if (act) { GET_KEY; GET_IDX; d = (k >> shift) & (RBUCK - 1); }          \
        u64 m = __ballot(act);                                                  \
        _Pragma("unroll")                                                       \
        for (int bit = 0; bit < RBITS; bit++) {                                 \
            u64 bb = __ballot(act && ((d >> bit) & 1));                         \
            m &= ((d >> bit) & 1) ? bb : ~bb;                                   \
        }                                                                       \
        int rw = __popcll(m & ((1ull << lane) - 1ull));                         \
        if (havenc) { cnt[t] = nc0; cnt[t + BLK] = nc1; }                       \
        if (act && rw == 0) whist[w][d] = (r << 20) | (int)__popcll(m);         \
        __syncthreads();                                                        \
        if (act) {                                                              \
            int off = cnt[d];                                                   \
            for (int w2 = 0; w2 < w; w2++) {                                    \
                int e = whist[w2][d];                                           \
                off += ((e >> 20) == r) ? (e & 0xFFFFF) : 0;                    \
            }                                                                   \
            dpair[off + rw] = ((u64)(uint32_t)k << 32) | (uint32_t)idx;         \
        }                                                                       \
        {                                                                       \
            int s0 = 0, s1 = 0;                                                 \
            _Pragma("unroll")                                                   \
            for (int w2 = 0; w2 < 4; w2++) {                                    \
                int e0 = whist[w2][t];                                          \
                int e1 = whist[w2][t + BLK];                                    \
                s0 += ((e0 >> 20) == r) ? (e0 & 0xFFFFF) : 0;                   \
                s1 += ((e1 >> 20) == r) ? (e1 & 0xFFFFF) : 0;                   \
            }                                                                   \
            nc0 = cnt[t] + s0; nc1 = cnt[t + BLK] + s1; havenc = true;          \
        }                                                                       \
        __syncthreads();                                                        \
    }

__global__ void kv10_scat0(const int* __restrict__ skey, u64* __restrict__ dpair,
                           const int* __restrict__ hist, const int* __restrict__ dtot,
                           int NP) {
    const int shift = 0;
    SCAT10_BODY(k = skey[i], idx = i)
}

__global__ void kv10_scatp(const u64* __restrict__ spair, u64* __restrict__ dpair,
                           const int* __restrict__ hist, const int* __restrict__ dtot,
                           int NP, int shift) {
    u64 pv;
    SCAT10_BODY(pv = spair[i]; k = (int)(pv >> 32), idx = (int)(pv & 0xFFFFFFFFull))
}

// Heads + valid counts with decoupled-lookback prefix (fuses old heads+scanG).
// Writes bsumH[b] = exclusive head prefix; last block writes G/nval/voxel_num.
// Also zero-fills the byte-flag array (set later by heads2 — separate kernel).
__global__ void kv10_heads(const u64* __restrict__ pair, int* __restrict__ bsumH,
                           u64* __restrict__ statusH, u64* __restrict__ flags8,
                           int* __restrict__ ctrl, float* __restrict__ out_vnum,
                           int NP, int NP8, int NB) {
    __shared__ int s[BLK];
    int TOTAL = ctrl[2];
    int t = threadIdx.x, b = blockIdx.x;
    int gid = b * BLK + t;
    if (gid < NP8) flags8[gid] = 0ull;
    int sbase = b * ELEMS + t * EPT;
    int hs = 0, vs = 0;
    if (sbase < NP) {
        int kprev = (sbase == 0) ? -1 : (int)(pair[sbase - 1] >> 32);
        #pragma unroll
        for (int r = 0; r < EPT; r++) {
            int i = sbase + r;
            if (i < NP) {
                int k = (int)(pair[i] >> 32);
                if (k != TOTAL) { vs++; hs += (k != kprev); }
                kprev = k;
            }
        }
    }
    s[t] = (hs << 16) | vs;                 // per-field block sums <= 2048, no carry
    __syncthreads();
    for (int o = BLK / 2; o > 0; o >>= 1) {
        if (t < o) s[t] += s[t + o];
        __syncthreads();
    }
    if (t == 0) {
        int tot_h = (s[0] >> 16) & 0xFFFF, tot_v = s[0] & 0xFFFF;
        u64 ih, iv;
        if (b == 0) {
            ih = (u64)tot_h; iv = (u64)tot_v;
            atomicExch(&statusH[0], FLAGX | (ih << 28) | iv);
            bsumH[0] = 0;
        } else {
            atomicExch(&statusH[b], FLAGP | ((u64)tot_h << 28) | (u64)tot_v);
            u64 run_h = 0, run_v = 0;
            int look = b - 1;
            long long guard = 0;
            while (look >= 0 && guard < (1ll << 36)) {
                u64 sv = atomicAdd(&statusH[look], 0ull);   // coherent read
                u64 f = sv >> 62;
                if (f == 0) { guard++; continue; }
                run_h += (sv >> 28) & M28;
                run_v += sv & M28;
                if (f == 2) break;                          // inclusive: stop
                look--;
            }
            ih = run_h + (u64)tot_h; iv = run_v + (u64)tot_v;
            atomicExch(&statusH[b], FLAGX | (ih << 28) | iv);
            bsumH[b] = (int)(ih - (u64)tot_h);
        }
        if (b == NB - 1) {
            int G = (int)ih, nval = (int)iv;
            ctrl[0] = G; ctrl[1] = nval;
            out_vnum[0] = (float)(G < MAXV ? G : MAXV);
        }
    }
}

// Emit per-group records (gstart, ghead, byte flag). One block scan; no atomics.
__global__ void kv10_heads2(const u64* __restrict__ pair, const int* __restrict__ bsumH,
                            int* __restrict__ gstart, int* __restrict__ ghead,
                            u64* __restrict__ flags8, const int* __restrict__ ctrl, int NP) {
    __shared__ int s[BLK];
    int TOTAL = ctrl[2];
    int t = threadIdx.x, b = blockIdx.x;
    int sbase = b * ELEMS + t * EPT;
    u64 pv[EPT];
    int hcnt = 0;
    unsigned hbits = 0;
    if (sbase < NP) {
        int kprev = (sbase == 0) ? -1 : (int)(pair[sbase - 1] >> 32);
        #pragma unroll
        for (int r = 0; r < EPT; r++) {
            int i = sbase + r;
            if (i < NP) {
                pv[r] = pair[i];
                int k = (int)(pv[r] >> 32);
                int h = (k != TOTAL) && (k != kprev);
                hbits |= (unsigned)h << r;
                hcnt += h;
                kprev = k;
            }
        }
    }
    s[t] = hcnt;
    __syncthreads();
    for (int o = 1; o < BLK; o <<= 1) {
        int x = (t >= o) ? s[t - o] : 0; __syncthreads();
        s[t] += x; __syncthreads();
    }
    if (sbase < NP && hbits) {
        int g = bsumH[b] + s[t] - hcnt;
        unsigned char* flags = (unsigned char*)flags8;
        #pragma unroll
        for (int r = 0; r < EPT; r++) {
            if ((hbits >> r) & 1) {
                gstart[g] = sbase + r;
                int io = (int)(pv[r] & 0xFFFFFFFFull);
                ghead[g] = io;
                flags[io] = 1;
                g++;
            }
        }
    }
}

// wpfx in ONE kernel: block bytesum + decoupled lookback + in-block scan.
__global__ void kv10_wp(const u64* __restrict__ flags8, int* __restrict__ wpfx,
                        u64* __restrict__ statusW, int NP8) {
    __shared__ int s[BLK];
    __shared__ int bexcl;
    int t = threadIdx.x, b = blockIdx.x;
    int i = b * BLK + t;
    u64 wv = (i < NP8) ? flags8[i] : 0ull;
    int v = (int)((wv * BYTEMUL) >> 56);
    s[t] = v;
    __syncthreads();
    for (int o = 1; o < BLK; o <<= 1) {
        int x = (t >= o) ? s[t - o] : 0; __syncthreads();
        s[t] += x; __syncthreads();
    }
    if (t == 0) {
        int tot = s[BLK - 1];
        if (b == 0) {
            atomicExch(&statusW[0], FLAGX | (u64)tot);
            bexcl = 0;
        } else {
            atomicExch(&statusW[b], FLAGP | (u64)tot);
            u64 run = 0;
            int look = b - 1;
            long long guard = 0;
            while (look >= 0 && guard < (1ll << 36)) {
                u64 sv = atomicAdd(&statusW[look], 0ull);
                u64 f = sv >> 62;
                if (f == 0) { guard++; continue; }
                run += sv & M28;
                if (f == 2) break;
                look--;
            }
            u64 incl = run + (u64)tot;
            atomicExch(&statusW[b], FLAGX | incl);
            bexcl = (int)(incl - (u64)tot);
        }
    }
    __syncthreads();
    if (i < NP8) wpfx[i] = bexcl + s[t] - v;
}

// Zero-fill voxels + coors + npv.
__global__ void kv10_zero(float4* __restrict__ out4, int n4) {
    int i = blockIdx.x * BLK + threadIdx.x;
    if (i < n4) out4[i] = make_float4(0.f, 0.f, 0.f, 0.f);
}

__device__ __forceinline__ int vox_rank(const u64* flags8, const int* wpfx, int io) {
    int w = io >> 3, b8 = io & 7;
    u64 below = flags8[w] & ((1ull << (8 * b8)) - 1ull);
    return wpfx[w] + (int)((below * BYTEMUL) >> 56);
}

// Fused emit: per-element group id via block scan + bsumH; heads write coors/npv.
__global__ void kv10_emit(const u64* __restrict__ pair, const int* __restrict__ gstart,
                          const int* __restrict__ ghead, const u64* __restrict__ flags8,
                          const int* __restrict__ wpfx, const int* __restrict__ ctrl,
                          const int* __restrict__ bsumH, const float* __restrict__ pts,
                          const float* __restrict__ vsz, const float* __restrict__ crg,
                          float* __restrict__ out, int NP) {
    __shared__ int s[BLK];
    int TOTAL = ctrl[2], G = ctrl[0], nval = ctrl[1];
    int t = threadIdx.x, b = blockIdx.x;
    int sbase = b * ELEMS + t * EPT;
    u64 pv[EPT];
    int hcnt = 0;
    unsigned hbits = 0;
    if (sbase < NP) {
        int kprev = (sbase == 0) ? -1 : (int)(pair[sbase - 1] >> 32);
        #pragma unroll
        for (int r = 0; r < EPT; r++) {
            int i = sbase + r;
            if (i < NP) {
                pv[r] = pair[i];
                int k = (int)(pv[r] >> 32);
                int h = (k != TOTAL) && (k != kprev);
                hbits |= (unsigned)h << r;
                hcnt += h;
                kprev = k;
            }
        }
    }
    s[t] = hcnt;
    __syncthreads();
    for (int o = 1; o < BLK; o <<= 1) {
        int x = (t >= o) ? s[t - o] : 0; __syncthreads();
        s[t] += x; __syncthreads();
    }
    if (sbase >= NP) return;
    int gg = bsumH[b] + (s[t] - hcnt) - 1;   // group of element BEFORE this chunk
    int gyd = (int)rintf((crg[4] - crg[1]) / vsz[1]);
    int gzd = (int)rintf((crg[5] - crg[2]) / vsz[2]);
    #pragma unroll
    for (int r = 0; r < EPT; r++) {
        int i = sbase + r;
        if (i >= NP) break;
        int h = (hbits >> r) & 1;
        gg += h;
        u64 p = pv[r];
        int k = (int)(p >> 32);
        if (k == TOTAL) continue;            // sorted suffix of invalids
        int p0 = gstart[gg];
        int vid = vox_rank(flags8, wpfx, ghead[gg]);
        if (vid >= MAXV) continue;
        if (h) {                             // per-voxel work (once per group)
            int cz = k % gzd; int rr = k / gzd; int cy = rr % gyd; int cx = rr / gyd;
            out[CO_OFF + vid * 3 + 0] = (float)cz;
            out[CO_OFF + vid * 3 + 1] = (float)cy;
            out[CO_OFF + vid * 3 + 2] = (float)cx;
            int nxt = (gg + 1 < G) ? gstart[gg + 1] : nval;
            int gsz = nxt - p0;
            out[NPV_OFF + vid] = (float)(gsz < MAXP ? gsz : MAXP);
        }
        int slot = i - p0;
        if (slot >= MAXP) continue;
        int iorig = (int)(p & 0xFFFFFFFFull);
        const float* src = pts + iorig * C;
        float* dst = out + (vid * MAXP + slot) * C;
        dst[0] = src[0]; dst[1] = src[1]; dst[2] = src[2]; dst[3] = src[3]; dst[4] = src[4];
    }
}

extern "C" void kernel_launch(void* const* d_in, const int* in_sizes, int n_in,
                              void* d_out, int out_size, void* d_ws, size_t ws_size,
                              hipStream_t stream) {
    if (!d_out || !d_ws || n_in < 3) return;
    const float* pts = (const float*)d_in[0];
    const float* vsz = (const float*)d_in[1];
    const float* crg = (const float*)d_in[2];
    if (!pts || !vsz || !crg) return;
    const int NP  = in_sizes[0] / C;
    if (NP <= 0) return;
    const int NB  = (NP + ELEMS - 1) / ELEMS;     // 2048-elem blocks (586)
    const int NP8 = (NP + 7) / 8;                 // byte-flag u64 words (150000)
    const int NWB = (NP8 + BLK - 1) / BLK;        // wp blocks (586)

    // Workspace budget (bytes); flags8 aliases hist (RBUCK*NB*4 >= NP8*8 always).
    size_t need = 2ull * NP * 8ull                          // pairA + pairB
                + (size_t)RBUCK * NB * 4ull                 // hist / flags8
                + (size_t)NB * 4ull                         // bsumH
                + (size_t)RBUCK * 4ull                      // dtot
                + (size_t)NP8 * 4ull                        // wpfx
                + 8ull * 4ull + 16ull                       // ctrl, pad
                + (size_t)NB * 8ull + (size_t)NWB * 8ull;   // statusH, statusW
    if (ws_size < need) return;
    if ((size_t)out_size < (size_t)VN_OFF + 1) return;

    u64* pairA = (u64*)d_ws;
    u64* pairB = pairA + NP;
    int* key0  = (int*)pairB;                     // aliases pairB (dead before pass 1 writes)
    int* w     = (int*)(pairB + NP);
    int* hist  = w; w += (size_t)RBUCK * NB;
    u64* flags8 = (u64*)hist;                     // aliases hist (dead after last scatter)
    int* bsumH = w; w += NB;
    int* dtot  = w; w += RBUCK;
    int* wpfx  = w; w += NP8;
    int* ctrl  = w; w += 8;
    w += ((uintptr_t)w & 7) ? 1 : 0;              // 8-byte align
    u64* statusH = (u64*)w;                       // NB words
    u64* statusW = statusH + NB;                  // NWB words

    float* out = (float*)d_out;

    kv10_linhist<<<NB, BLK, 0, stream>>>(pts, vsz, crg, key0, hist, ctrl,
                                         statusH, statusW, NP, NB, NWB);
    kv10_zero<<<(VN_OFF / 4 + BLK - 1) / BLK, BLK, 0, stream>>>((float4*)out, VN_OFF / 4);

    // Pass 0: key0 (int) -> pairA
    kv10_scanb<<<RBUCK, BLK, 0, stream>>>(hist, dtot, NB);
    kv10_scat0<<<NB, BLK, 0, stream>>>(key0, pairA, hist, dtot, NP);
    // Pass 1: pairA -> pairB (clobbers key0 — dead)
    kv10_hist_p<<<NB, BLK, 0, stream>>>(pairA, hist, NP, RBITS);
    kv10_scanb<<<RBUCK, BLK, 0, stream>>>(hist, dtot, NB);
    kv10_scatp<<<NB, BLK, 0, stream>>>(pairA, pairB, hist, dtot, NP, RBITS);
    // Pass 2: pairB -> pairA (final sorted order)
    kv10_hist_p<<<NB, BLK, 0, stream>>>(pairB, hist, NP, 2 * RBITS);
    kv10_scanb<<<RBUCK, BLK, 0, stream>>>(hist, dtot, NB);
    kv10_scatp<<<NB, BLK, 0, stream>>>(pairB, pairA, hist, dtot, NP, 2 * RBITS);

    int* gstart = (int*)pairB;                    // pairB free after pass 2
    int* ghead  = gstart + NP;

    kv10_heads<<<NB, BLK, 0, stream>>>(pairA, bsumH, statusH, flags8, ctrl,
                                       out + VN_OFF, NP, NP8, NB);
    kv10_heads2<<<NB, BLK, 0, stream>>>(pairA, bsumH, gstart, ghead, flags8, ctrl, NP);
    kv10_wp<<<NWB, BLK, 0, stream>>>(flags8, wpfx, statusW, NP8);
    kv10_emit<<<NB, BLK, 0, stream>>>(pairA, gstart, ghead, flags8, wpfx, ctrl,
                                      bsumH, pts, vsz, crg, out, NP);
}